// Round 6
// baseline (234.944 us; speedup 1.0000x reference)
//
#include <hip/hip_runtime.h>
#include <math.h>

// P=256, T=65536, UNITS=128, WIDTH=1.0
#define Pn 256
#define Tn 65536
#define Un 128
#define NC 512          // scan chunks
#define CHUNK 128       // Tn / NC
#define ST 32           // GEMM sub-tile depth

typedef float f4 __attribute__((ext_vector_type(4)));
typedef float f2 __attribute__((ext_vector_type(2)));

// ---------------------------------------------------------------------------
// Play step: s' = Phi(x - s) + s  ==  min(max(s, x), x+1).
// Operator (A,B): s -> min(max(s,A),B). Single element x: (x, x+1).
// compose(op1 THEN op2): A = max(A1,A2); B = min(max(B1,A2),B2).
// ---------------------------------------------------------------------------

// kA: one wave per (p, chunk). Coalesced f2 loads (512B/wave), lane composes
// its 2 ordered elements, then ordered 6-step shfl_down tree (left=self).
__global__ __launch_bounds__(1024) void kA(const float* __restrict__ in,
                                           const float* __restrict__ pw,
                                           f2* __restrict__ AB) {
  const int tid = threadIdx.x;
  const int W = blockIdx.x * 16 + (tid >> 6);  // global wave id, [0, Pn*NC)
  const int l = tid & 63;
  const int c = W & (NC - 1);
  const int p = W >> 9;                        // W / NC
  const float w = pw[p];
  f2 v = *(const f2*)(in + (size_t)p * Tn + (size_t)c * CHUNK + 2 * l);
  const float x0 = v.x * w, x1 = v.y * w;
  float A = fmaxf(x0, x1);
  float B = fminf(fmaxf(x0 + 1.0f, x1), x1 + 1.0f);
#pragma unroll
  for (int off = 1; off < 64; off <<= 1) {
    float A2 = __shfl_down(A, off);
    float B2 = __shfl_down(B, off);
    B = fminf(fmaxf(B, A2), B2);   // old B with received (A2,B2)
    A = fmaxf(A, A2);
  }
  if (l == 0) {
    f2 r; r.x = A; r.y = B;
    AB[(size_t)c * Pn + p] = r;
  }
}

// kB: two-level scan over chunk operators. 1024 thr = (p, quarter q).
// Phase1: compose quarter ops. Phase2: 256 thr scan 4 quarter ops.
// Phase3: rescan quarter, writing incoming state per chunk.
__global__ __launch_bounds__(1024) void kB(const f2* __restrict__ AB,
                                           const float* __restrict__ st,
                                           float* __restrict__ sinb) {
  __shared__ float qA[4][Pn], qB[4][Pn], sq[4][Pn];
  const int p = threadIdx.x & 255, q = threadIdx.x >> 8;
  const int c0 = q * (NC / 4);
  float A = -3.402823466e38f, B = 3.402823466e38f;
  for (int j = 0; j < NC / 4; ++j) {
    f2 ab = AB[(size_t)(c0 + j) * Pn + p];
    B = fminf(fmaxf(B, ab.x), ab.y);
    A = fmaxf(A, ab.x);
  }
  qA[q][p] = A;
  qB[q][p] = B;
  __syncthreads();
  if (threadIdx.x < Pn) {
    float s = st[p];
#pragma unroll
    for (int qq = 0; qq < 4; ++qq) {
      sq[qq][p] = s;
      s = fminf(fmaxf(s, qA[qq][p]), qB[qq][p]);
    }
  }
  __syncthreads();
  float s = sq[q][p];
  for (int j = 0; j < NC / 4; ++j) {
    sinb[(size_t)(c0 + j) * Pn + p] = s;
    f2 ab = AB[(size_t)(c0 + j) * Pn + p];
    s = fminf(fmaxf(s, ab.x), ab.y);
  }
}

// kC: rescan CPG chunks with correct incoming state + fused f32 GEMM.
// 512 threads (8 waves). Scan: threads 0..255, one row each.
// GEMM: thread (pg=tid>>4, ug=tid&15) owns p in {pg*4+a+k1*128},
// u in {ug*4+l+k2*64}: acc[2][4][2][4]=64 VGPR.
// LDS reads: sS quads -> 16-lane broadcast groups (conflict-free);
// sK ug*4 offsets -> 2-way alias (free).
template <int CPG, bool ATOMIC>
__global__ __launch_bounds__(512, 4) void kC(const float* __restrict__ in,
                                             const float* __restrict__ pw,
                                             const float* __restrict__ Kg,
                                             const float* __restrict__ sinb,
                                             float* __restrict__ outp) {
  __shared__ float sS[ST][Pn];   // 32 KB
  __shared__ float sK[ST][Un];   // 16 KB
  const int tid = threadIdx.x;
  const int c0 = blockIdx.x * CPG;

  float w = 0.0f, s = 0.0f;
  const f4* src = nullptr;
  if (tid < Pn) {
    w = pw[tid];
    s = sinb[(size_t)c0 * Pn + tid];
    src = (const f4*)(in + (size_t)tid * Tn + (size_t)c0 * CHUNK);
  }

  const int ug = tid & 15, pg = tid >> 4;
  float acc[2][4][2][4];
#pragma unroll
  for (int k1 = 0; k1 < 2; ++k1)
#pragma unroll
    for (int a = 0; a < 4; ++a)
#pragma unroll
      for (int k2 = 0; k2 < 2; ++k2)
#pragma unroll
        for (int l = 0; l < 4; ++l) acc[k1][a][k2][l] = 0.0f;

  const int nsub = (CHUNK * CPG) / ST;
  for (int sub = 0; sub < nsub; ++sub) {
    // stage K rows [c0*CHUNK + sub*ST, +ST): 1024 f4 / 512 thr = 2 each
    const f4* Kt = (const f4*)(Kg + ((size_t)c0 * CHUNK + sub * ST) * Un);
#pragma unroll
    for (int k = 0; k < 2; ++k) {
      int idx = k * 512 + tid;
      int r = idx >> 5, col = idx & 31;
      *(f4*)&sK[r][col * 4] = Kt[r * 32 + col];
    }
    // scan ST elements of own row (threads 0..255)
    if (tid < Pn) {
#pragma unroll
      for (int i4 = 0; i4 < ST / 4; ++i4) {
        f4 v = src[sub * (ST / 4) + i4];
#pragma unroll
        for (int j = 0; j < 4; ++j) {
          float x = v[j] * w;
          s = fminf(fmaxf(s, x), x + 1.0f);   // min LAST
          sS[i4 * 4 + j][tid] = s;
        }
      }
    }
    __syncthreads();
#pragma unroll 2
    for (int i = 0; i < ST; ++i) {
      f4 sv0 = *(const f4*)&sS[i][pg * 4];
      f4 sv1 = *(const f4*)&sS[i][128 + pg * 4];
      f4 kv0 = *(const f4*)&sK[i][ug * 4];
      f4 kv1 = *(const f4*)&sK[i][64 + ug * 4];
#pragma unroll
      for (int a = 0; a < 4; ++a) {
        float s0 = sv0[a], s1 = sv1[a];
#pragma unroll
        for (int l = 0; l < 4; ++l) {
          acc[0][a][0][l] += s0 * kv0[l];
          acc[0][a][1][l] += s0 * kv1[l];
          acc[1][a][0][l] += s1 * kv0[l];
          acc[1][a][1][l] += s1 * kv1[l];
        }
      }
    }
    __syncthreads();
  }

  if (ATOMIC) {
#pragma unroll
    for (int k1 = 0; k1 < 2; ++k1)
#pragma unroll
      for (int a = 0; a < 4; ++a) {
        int pp = k1 * 128 + pg * 4 + a;
#pragma unroll
        for (int k2 = 0; k2 < 2; ++k2)
#pragma unroll
          for (int l = 0; l < 4; ++l)
            atomicAdd(&outp[(size_t)pp * Un + k2 * 64 + ug * 4 + l],
                      acc[k1][a][k2][l]);
      }
  } else {
    float* base = outp + (size_t)blockIdx.x * (Pn * Un);
#pragma unroll
    for (int k1 = 0; k1 < 2; ++k1)
#pragma unroll
      for (int a = 0; a < 4; ++a) {
        int pp = k1 * 128 + pg * 4 + a;
#pragma unroll
        for (int k2 = 0; k2 < 2; ++k2) {
          f4 v;
#pragma unroll
          for (int l = 0; l < 4; ++l) v[l] = acc[k1][a][k2][l];
          *(f4*)&base[(size_t)pp * Un + k2 * 64 + ug * 4] = v;
        }
      }
  }
}

// kD: reduce NP partial planes + bias + tanh. Block = 64 outputs x 4 c-planes.
template <int NP>
__global__ __launch_bounds__(256) void kD(const float* __restrict__ part,
                                          const float* __restrict__ bias,
                                          float* __restrict__ out) {
  __shared__ float red[4][64];
  const int tid = threadIdx.x;
  const int o = tid & 63, qc = tid >> 6;
  const int g = blockIdx.x * 64 + o;
  float a = 0.0f;
#pragma unroll 4
  for (int k = 0; k < NP / 4; ++k)
    a += part[(size_t)(qc + 4 * k) * (Pn * Un) + g];
  red[qc][o] = a;
  __syncthreads();
  if (tid < 64) {
    float t = red[0][o] + red[1][o] + red[2][o] + red[3][o];
    out[g] = tanhf(t + bias[g & (Un - 1)]);
  }
}

// tanh finisher for atomic last-resort path
__global__ __launch_bounds__(256) void kD2(float* __restrict__ out,
                                           const float* __restrict__ bias) {
  const int g = blockIdx.x * 256 + threadIdx.x;
  out[g] = tanhf(out[g] + bias[g & (Un - 1)]);
}

// ---------------------------------------------------------------------------
extern "C" void kernel_launch(void* const* d_in, const int* in_sizes, int n_in,
                              void* d_out, int out_size, void* d_ws,
                              size_t ws_size, hipStream_t stream) {
  const float* in   = (const float*)d_in[0];  // [P, T]
  const float* pw   = (const float*)d_in[1];  // [P]
  const float* Kg   = (const float*)d_in[2];  // [T, U]
  const float* bias = (const float*)d_in[3];  // [U]
  const float* st   = (const float*)d_in[4];  // [P]
  float* out = (float*)d_out;                 // [P, U]
  float* wsf = (float*)d_ws;

  f2* AB      = (f2*)wsf;                     // NC*Pn f2     (1 MB)
  float* sinb = wsf + 2 * NC * Pn;            // NC*Pn floats (0.5 MB)
  float* part = wsf + 3 * NC * Pn;            // partial planes

  const size_t base_f = (size_t)3 * NC * Pn;
  const size_t need1 = (base_f + (size_t)NC * Pn * Un) * 4;        // ~68.6 MB
  const size_t need2 = (base_f + (size_t)(NC / 2) * Pn * Un) * 4;  // ~35.1 MB

  kA<<<(Pn * NC) / 16, 1024, 0, stream>>>(in, pw, AB);
  kB<<<1, 1024, 0, stream>>>(AB, st, sinb);

  if (ws_size >= need1) {
    kC<1, false><<<NC, 512, 0, stream>>>(in, pw, Kg, sinb, part);
    kD<NC><<<(Pn * Un) / 64, 256, 0, stream>>>(part, bias, out);
  } else if (ws_size >= need2) {
    kC<2, false><<<NC / 2, 512, 0, stream>>>(in, pw, Kg, sinb, part);
    kD<NC / 2><<<(Pn * Un) / 64, 256, 0, stream>>>(part, bias, out);
  } else {
    hipMemsetAsync(out, 0, (size_t)Pn * Un * sizeof(float), stream);
    kC<2, true><<<NC / 2, 512, 0, stream>>>(in, pw, Kg, sinb, out);
    kD2<<<(Pn * Un) / 256, 256, 0, stream>>>(out, bias);
  }
}

// Round 8
// 201.404 us; speedup vs baseline: 1.1665x; 1.1665x over previous
//
#include <hip/hip_runtime.h>
#include <math.h>

// P=256, T=65536, UNITS=128, WIDTH=1.0
#define Pn 256
#define Tn 65536
#define Un 128
#define NC 512          // scan chunks
#define CHUNK 128       // Tn / NC
#define ST 16           // GEMM sub-tile depth (double-buffered)

typedef float f4 __attribute__((ext_vector_type(4)));
typedef float f2 __attribute__((ext_vector_type(2)));

// ---------------------------------------------------------------------------
// Play step: s' = Phi(x - s) + s  ==  min(max(s, x), x+1)   [min LAST].
// Operator (A,B): s -> min(max(s,A),B). Element x -> (x, x+1).
// compose(first=(A1,B1), then=(A2,B2)): A = max(A1,A2); B = min(max(B1,A2),B2).
// Exact for arbitrary reals as long as application order is min(max(s,A),B).
// ---------------------------------------------------------------------------

// kA: one wave per (p, chunk). Coalesced f2 loads (512B/wave), lane composes
// its 2 ordered elements, then ordered 6-step shfl_down tree (self=first).
// Writes operators row-major AB[p][c] for kB's contiguous per-row read.
__global__ __launch_bounds__(1024) void kA(const float* __restrict__ in,
                                           const float* __restrict__ pw,
                                           f2* __restrict__ AB) {
  const int tid = threadIdx.x;
  const int W = blockIdx.x * 16 + (tid >> 6);  // global wave id, [0, Pn*NC)
  const int l = tid & 63;
  const int c = W & (NC - 1);
  const int p = W >> 9;                        // W / NC
  const float w = pw[p];
  f2 v = *(const f2*)(in + (size_t)p * Tn + (size_t)c * CHUNK + 2 * l);
  const float x0 = v.x * w, x1 = v.y * w;
  float A = fmaxf(x0, x1);
  float B = fminf(fmaxf(x0 + 1.0f, x1), x1 + 1.0f);
#pragma unroll
  for (int off = 1; off < 64; off <<= 1) {
    float A2 = __shfl_down(A, off);   // received = "then" (later elements)
    float B2 = __shfl_down(B, off);
    B = fminf(fmaxf(B, A2), B2);
    A = fmaxf(A, A2);
  }
  if (l == 0) {
    f2 r; r.x = A; r.y = B;
    AB[(size_t)p * NC + c] = r;
  }
}

// kB: per-row parallel (Hillis-Steele) inclusive scan over NC chunk operators.
// 256 blocks (one per row p), NC threads. Non-commutative compose, left=first.
// Thread c writes the INCOMING state of chunk c: sinb[c][p].
__global__ __launch_bounds__(NC) void kB(const f2* __restrict__ AB,
                                         const float* __restrict__ st,
                                         float* __restrict__ sinb) {
  __shared__ float sA[NC], sB[NC];
  const int p = blockIdx.x;
  const int c = threadIdx.x;
  f2 ab = AB[(size_t)p * NC + c];
  sA[c] = ab.x;
  sB[c] = ab.y;
  __syncthreads();
#pragma unroll
  for (int d = 1; d < NC; d <<= 1) {
    float aL = 0.0f, bL = 0.0f;
    const bool has = (c >= d);
    if (has) { aL = sA[c - d]; bL = sB[c - d]; }
    __syncthreads();
    if (has) {
      float aS = sA[c], bS = sB[c];
      sB[c] = fminf(fmaxf(bL, aS), bS);   // compose(left THEN self)
      sA[c] = fmaxf(aL, aS);
    }
    __syncthreads();
  }
  const float s0 = st[p];
  const float sin_c =
      (c == 0) ? s0 : fminf(fmaxf(s0, sA[c - 1]), sB[c - 1]);
  sinb[(size_t)c * Pn + p] = sin_c;
}

// kC: rescan chunk with correct incoming state + fused f32 GEMM.
// 512 threads (8 waves). Double-buffered LDS (ST=16) with async-stage split:
// issue next-subtile global loads into regs BEFORE the GEMM (latency hides
// under ~2000 cycles of FMA), write regs->LDS after, ONE barrier per subtile.
// GEMM: thread (pg=tid>>4, ug=tid&15) owns p in {k1*128+pg*4+a},
// u in {k2*64+ug*4+l}: acc[2][4][2][4] = 64 VGPR.
template <int CPG, bool ATOMIC>
__global__ __launch_bounds__(512, 4) void kC(const float* __restrict__ in,
                                             const float* __restrict__ pw,
                                             const float* __restrict__ Kg,
                                             const float* __restrict__ sinb,
                                             float* __restrict__ outp) {
  __shared__ float sS[2][ST][Pn];   // 32 KB
  __shared__ float sK[2][ST][Un];   // 16 KB
  const int tid = threadIdx.x;
  const int c0 = blockIdx.x * CPG;

  float w = 0.0f, s = 0.0f;
  const f4* src = nullptr;
  if (tid < Pn) {
    w = pw[tid];
    s = sinb[(size_t)c0 * Pn + tid];
    src = (const f4*)(in + (size_t)tid * Tn + (size_t)c0 * CHUNK);
  }

  const int ug = tid & 15, pg = tid >> 4;
  const int kr = tid >> 5, kcol = tid & 31;   // K-stage: 16 rows x 32 f4
  const f4* Kt = (const f4*)(Kg + (size_t)c0 * CHUNK * Un);

  float acc[2][4][2][4];
#pragma unroll
  for (int k1 = 0; k1 < 2; ++k1)
#pragma unroll
    for (int a = 0; a < 4; ++a)
#pragma unroll
      for (int k2 = 0; k2 < 2; ++k2)
#pragma unroll
        for (int l = 0; l < 4; ++l) acc[k1][a][k2][l] = 0.0f;

  const int nsub = (CHUNK * CPG) / ST;

  // ---- prologue: stage subtile 0 into buffer 0
  {
    f4 kv = Kt[kr * 32 + kcol];
    *(f4*)&sK[0][kr][kcol * 4] = kv;
    if (tid < Pn) {
#pragma unroll
      for (int i4 = 0; i4 < ST / 4; ++i4) {
        f4 v = src[i4];
#pragma unroll
        for (int j = 0; j < 4; ++j) {
          float x = v[j] * w;
          s = fminf(fmaxf(s, x), x + 1.0f);
          sS[0][i4 * 4 + j][tid] = s;
        }
      }
    }
  }
  __syncthreads();

  int b = 0;
  for (int sub = 0; sub < nsub; ++sub) {
    // issue next-subtile global loads (stay in flight through the GEMM)
    f4 kpre;
    f4 spre0, spre1, spre2, spre3;
    const bool more = (sub + 1 < nsub);
    if (more) {
      kpre = Kt[(sub + 1) * (ST * Un / 4) + kr * 32 + kcol];
      if (tid < Pn) {
        spre0 = src[(sub + 1) * (ST / 4) + 0];
        spre1 = src[(sub + 1) * (ST / 4) + 1];
        spre2 = src[(sub + 1) * (ST / 4) + 2];
        spre3 = src[(sub + 1) * (ST / 4) + 3];
      }
    }

    // GEMM on buffer b
    const float(*cs)[Pn] = sS[b];
    const float(*ck)[Un] = sK[b];
#pragma unroll 4
    for (int i = 0; i < ST; ++i) {
      f4 sv0 = *(const f4*)&cs[i][pg * 4];
      f4 sv1 = *(const f4*)&cs[i][128 + pg * 4];
      f4 kv0 = *(const f4*)&ck[i][ug * 4];
      f4 kv1 = *(const f4*)&ck[i][64 + ug * 4];
#pragma unroll
      for (int a = 0; a < 4; ++a) {
        float s0v = sv0[a], s1v = sv1[a];
#pragma unroll
        for (int l = 0; l < 4; ++l) {
          acc[0][a][0][l] += s0v * kv0[l];
          acc[0][a][1][l] += s0v * kv1[l];
          acc[1][a][0][l] += s1v * kv0[l];
          acc[1][a][1][l] += s1v * kv1[l];
        }
      }
    }

    // write prefetched data into the other buffer (loads complete here)
    if (more) {
      *(f4*)&sK[b ^ 1][kr][kcol * 4] = kpre;
      if (tid < Pn) {
        f4 pv[4] = {spre0, spre1, spre2, spre3};
#pragma unroll
        for (int i4 = 0; i4 < ST / 4; ++i4) {
#pragma unroll
          for (int j = 0; j < 4; ++j) {
            float x = pv[i4][j] * w;
            s = fminf(fmaxf(s, x), x + 1.0f);
            sS[b ^ 1][i4 * 4 + j][tid] = s;
          }
        }
      }
    }
    __syncthreads();
    b ^= 1;
  }

  if (ATOMIC) {
#pragma unroll
    for (int k1 = 0; k1 < 2; ++k1)
#pragma unroll
      for (int a = 0; a < 4; ++a) {
        int pp = k1 * 128 + pg * 4 + a;
#pragma unroll
        for (int k2 = 0; k2 < 2; ++k2)
#pragma unroll
          for (int l = 0; l < 4; ++l)
            atomicAdd(&outp[(size_t)pp * Un + k2 * 64 + ug * 4 + l],
                      acc[k1][a][k2][l]);
      }
  } else {
    float* base = outp + (size_t)blockIdx.x * (Pn * Un);
#pragma unroll
    for (int k1 = 0; k1 < 2; ++k1)
#pragma unroll
      for (int a = 0; a < 4; ++a) {
        int pp = k1 * 128 + pg * 4 + a;
#pragma unroll
        for (int k2 = 0; k2 < 2; ++k2) {
          f4 v;
#pragma unroll
          for (int l = 0; l < 4; ++l) v[l] = acc[k1][a][k2][l];
          *(f4*)&base[(size_t)pp * Un + k2 * 64 + ug * 4] = v;
        }
      }
  }
}

// kD: reduce NP partial planes + bias + tanh. Block = 64 outputs x 4 c-planes.
template <int NP>
__global__ __launch_bounds__(256) void kD(const float* __restrict__ part,
                                          const float* __restrict__ bias,
                                          float* __restrict__ out) {
  __shared__ float red[4][64];
  const int tid = threadIdx.x;
  const int o = tid & 63, qc = tid >> 6;
  const int g = blockIdx.x * 64 + o;
  float a = 0.0f;
#pragma unroll 4
  for (int k = 0; k < NP / 4; ++k)
    a += part[(size_t)(qc + 4 * k) * (Pn * Un) + g];
  red[qc][o] = a;
  __syncthreads();
  if (tid < 64) {
    float t = red[0][o] + red[1][o] + red[2][o] + red[3][o];
    out[g] = tanhf(t + bias[g & (Un - 1)]);
  }
}

// tanh finisher for atomic last-resort path
__global__ __launch_bounds__(256) void kD2(float* __restrict__ out,
                                           const float* __restrict__ bias) {
  const int g = blockIdx.x * 256 + threadIdx.x;
  out[g] = tanhf(out[g] + bias[g & (Un - 1)]);
}

// ---------------------------------------------------------------------------
extern "C" void kernel_launch(void* const* d_in, const int* in_sizes, int n_in,
                              void* d_out, int out_size, void* d_ws,
                              size_t ws_size, hipStream_t stream) {
  const float* in   = (const float*)d_in[0];  // [P, T]
  const float* pw   = (const float*)d_in[1];  // [P]
  const float* Kg   = (const float*)d_in[2];  // [T, U]
  const float* bias = (const float*)d_in[3];  // [U]
  const float* st   = (const float*)d_in[4];  // [P]
  float* out = (float*)d_out;                 // [P, U]
  float* wsf = (float*)d_ws;

  f2* AB      = (f2*)wsf;                     // Pn*NC f2     (1 MB)
  float* sinb = wsf + 2 * NC * Pn;            // NC*Pn floats (0.5 MB)
  float* part = wsf + 3 * NC * Pn;            // partial planes

  const size_t base_f = (size_t)3 * NC * Pn;
  const size_t need1 = (base_f + (size_t)NC * Pn * Un) * 4;        // ~68.6 MB
  const size_t need2 = (base_f + (size_t)(NC / 2) * Pn * Un) * 4;  // ~35.1 MB

  kA<<<(Pn * NC) / 16, 1024, 0, stream>>>(in, pw, AB);
  kB<<<Pn, NC, 0, stream>>>(AB, st, sinb);

  if (ws_size >= need1) {
    kC<1, false><<<NC, 512, 0, stream>>>(in, pw, Kg, sinb, part);
    kD<NC><<<(Pn * Un) / 64, 256, 0, stream>>>(part, bias, out);
  } else if (ws_size >= need2) {
    kC<2, false><<<NC / 2, 512, 0, stream>>>(in, pw, Kg, sinb, part);
    kD<NC / 2><<<(Pn * Un) / 64, 256, 0, stream>>>(part, bias, out);
  } else {
    hipMemsetAsync(out, 0, (size_t)Pn * Un * sizeof(float), stream);
    kC<2, true><<<NC / 2, 512, 0, stream>>>(in, pw, Kg, sinb, out);
    kD2<<<(Pn * Un) / 256, 256, 0, stream>>>(out, bias);
  }
}

// Round 9
// 189.668 us; speedup vs baseline: 1.2387x; 1.0619x over previous
//
#include <hip/hip_runtime.h>
#include <math.h>

// P=256, T=65536, UNITS=128, WIDTH=1.0
#define Pn 256
#define Tn 65536
#define Un 128
#define NC 512          // scan chunks (kC grid)
#define CHUNK 128       // Tn / NC
#define ST 16           // kC GEMM sub-tile depth (double-buffered)
#define SEG 64          // elements per kAB thread

typedef float f4 __attribute__((ext_vector_type(4)));

// ---------------------------------------------------------------------------
// Play step: s' = Phi(x - s) + s  ==  min(max(s, x), x+1)   [min LAST].
// Operator (A,B): s -> min(max(s,A),B). Element x -> (x, x+1).
// compose(first=(A1,B1), then=(A2,B2)): A = max(A1,A2); B = min(max(B1,A2),B2).
// ---------------------------------------------------------------------------

// kAB: fused chunk-operator build + operator scan. One block per row p.
// 1024 threads x SEG=64 contiguous elements each. Hierarchical scan:
// 6-step shfl_up in-wave inclusive scan -> 16 wave totals in LDS ->
// thread 0 walks states across waves -> exclusive-op application.
// Even threads write the incoming state of chunk t/2 (chunk = 2 segments).
__global__ __launch_bounds__(1024) void kAB(const float* __restrict__ in,
                                            const float* __restrict__ pw,
                                            const float* __restrict__ st,
                                            float* __restrict__ sinb) {
  __shared__ float wA[16], wB[16], sw[16];
  const int p = blockIdx.x;
  const int t = threadIdx.x;
  const int lane = t & 63, w = t >> 6;
  const float wgt = pw[p];
  const f4* src = (const f4*)(in + (size_t)p * Tn + (size_t)t * SEG);

  // segment operator (sequential compose over 64 elements, min LAST)
  float A = -3.402823466e38f, B = 3.402823466e38f;
#pragma unroll
  for (int i = 0; i < SEG / 4; ++i) {
    f4 v = src[i];
#pragma unroll
    for (int j = 0; j < 4; ++j) {
      float x = v[j] * wgt;
      A = fmaxf(A, x);
      B = fminf(fmaxf(B, x), x + 1.0f);
    }
  }

  // in-wave inclusive operator scan (lane ascending = time ascending)
#pragma unroll
  for (int off = 1; off < 64; off <<= 1) {
    float Ar = __shfl_up(A, off);
    float Br = __shfl_up(B, off);
    if (lane >= off) {
      B = fminf(fmaxf(Br, A), B);   // compose(first=received, then=self)
      A = fmaxf(Ar, A);
    }
  }
  if (lane == 63) { wA[w] = A; wB[w] = B; }
  __syncthreads();

  // states at wave boundaries (16 serial steps, one thread)
  if (t == 0) {
    float s = st[p];
#pragma unroll
    for (int q = 0; q < 16; ++q) {
      sw[q] = s;
      s = fminf(fmaxf(s, wA[q]), wB[q]);
    }
  }
  __syncthreads();

  // incoming state of this thread's segment = apply exclusive op to sw[w]
  float Ae = __shfl_up(A, 1);
  float Be = __shfl_up(B, 1);
  float s_in = (lane == 0) ? sw[w] : fminf(fmaxf(sw[w], Ae), Be);

  if ((t & 1) == 0)
    sinb[(size_t)(t >> 1) * Pn + p] = s_in;   // chunk c = t/2, layout [c][p]
}

// ---------------------------------------------------------------------------
// kC: rescan chunk with correct incoming state + fused f32 GEMM.
// 512 threads (8 waves). Double-buffered LDS (ST=16), async-stage split:
// next-subtile global loads issued BEFORE the GEMM, written after, one
// barrier per subtile. Thread (pg,ug) owns p in {k1*128+pg*4+a},
// u in {k2*64+ug*4+l}: acc[2][4][2][4] = 64 VGPR.  (unchanged from R8)
// ---------------------------------------------------------------------------
template <int CPG, bool ATOMIC>
__global__ __launch_bounds__(512, 4) void kC(const float* __restrict__ in,
                                             const float* __restrict__ pw,
                                             const float* __restrict__ Kg,
                                             const float* __restrict__ sinb,
                                             float* __restrict__ outp) {
  __shared__ float sS[2][ST][Pn];   // 32 KB
  __shared__ float sK[2][ST][Un];   // 16 KB
  const int tid = threadIdx.x;
  const int c0 = blockIdx.x * CPG;

  float w = 0.0f, s = 0.0f;
  const f4* src = nullptr;
  if (tid < Pn) {
    w = pw[tid];
    s = sinb[(size_t)c0 * Pn + tid];
    src = (const f4*)(in + (size_t)tid * Tn + (size_t)c0 * CHUNK);
  }

  const int ug = tid & 15, pg = tid >> 4;
  const int kr = tid >> 5, kcol = tid & 31;   // K-stage: 16 rows x 32 f4
  const f4* Kt = (const f4*)(Kg + (size_t)c0 * CHUNK * Un);

  float acc[2][4][2][4];
#pragma unroll
  for (int k1 = 0; k1 < 2; ++k1)
#pragma unroll
    for (int a = 0; a < 4; ++a)
#pragma unroll
      for (int k2 = 0; k2 < 2; ++k2)
#pragma unroll
        for (int l = 0; l < 4; ++l) acc[k1][a][k2][l] = 0.0f;

  const int nsub = (CHUNK * CPG) / ST;

  // prologue: stage subtile 0 into buffer 0
  {
    f4 kv = Kt[kr * 32 + kcol];
    *(f4*)&sK[0][kr][kcol * 4] = kv;
    if (tid < Pn) {
#pragma unroll
      for (int i4 = 0; i4 < ST / 4; ++i4) {
        f4 v = src[i4];
#pragma unroll
        for (int j = 0; j < 4; ++j) {
          float x = v[j] * w;
          s = fminf(fmaxf(s, x), x + 1.0f);
          sS[0][i4 * 4 + j][tid] = s;
        }
      }
    }
  }
  __syncthreads();

  int b = 0;
  for (int sub = 0; sub < nsub; ++sub) {
    f4 kpre;
    f4 spre0, spre1, spre2, spre3;
    const bool more = (sub + 1 < nsub);
    if (more) {
      kpre = Kt[(sub + 1) * (ST * Un / 4) + kr * 32 + kcol];
      if (tid < Pn) {
        spre0 = src[(sub + 1) * (ST / 4) + 0];
        spre1 = src[(sub + 1) * (ST / 4) + 1];
        spre2 = src[(sub + 1) * (ST / 4) + 2];
        spre3 = src[(sub + 1) * (ST / 4) + 3];
      }
    }

    const float(*cs)[Pn] = sS[b];
    const float(*ck)[Un] = sK[b];
#pragma unroll 4
    for (int i = 0; i < ST; ++i) {
      f4 sv0 = *(const f4*)&cs[i][pg * 4];
      f4 sv1 = *(const f4*)&cs[i][128 + pg * 4];
      f4 kv0 = *(const f4*)&ck[i][ug * 4];
      f4 kv1 = *(const f4*)&ck[i][64 + ug * 4];
#pragma unroll
      for (int a = 0; a < 4; ++a) {
        float s0v = sv0[a], s1v = sv1[a];
#pragma unroll
        for (int l = 0; l < 4; ++l) {
          acc[0][a][0][l] += s0v * kv0[l];
          acc[0][a][1][l] += s0v * kv1[l];
          acc[1][a][0][l] += s1v * kv0[l];
          acc[1][a][1][l] += s1v * kv1[l];
        }
      }
    }

    if (more) {
      *(f4*)&sK[b ^ 1][kr][kcol * 4] = kpre;
      if (tid < Pn) {
        f4 pv[4] = {spre0, spre1, spre2, spre3};
#pragma unroll
        for (int i4 = 0; i4 < ST / 4; ++i4) {
#pragma unroll
          for (int j = 0; j < 4; ++j) {
            float x = pv[i4][j] * w;
            s = fminf(fmaxf(s, x), x + 1.0f);
            sS[b ^ 1][i4 * 4 + j][tid] = s;
          }
        }
      }
    }
    __syncthreads();
    b ^= 1;
  }

  if (ATOMIC) {
#pragma unroll
    for (int k1 = 0; k1 < 2; ++k1)
#pragma unroll
      for (int a = 0; a < 4; ++a) {
        int pp = k1 * 128 + pg * 4 + a;
#pragma unroll
        for (int k2 = 0; k2 < 2; ++k2)
#pragma unroll
          for (int l = 0; l < 4; ++l)
            atomicAdd(&outp[(size_t)pp * Un + k2 * 64 + ug * 4 + l],
                      acc[k1][a][k2][l]);
      }
  } else {
    float* base = outp + (size_t)blockIdx.x * (Pn * Un);
#pragma unroll
    for (int k1 = 0; k1 < 2; ++k1)
#pragma unroll
      for (int a = 0; a < 4; ++a) {
        int pp = k1 * 128 + pg * 4 + a;
#pragma unroll
        for (int k2 = 0; k2 < 2; ++k2) {
          f4 v;
#pragma unroll
          for (int l = 0; l < 4; ++l) v[l] = acc[k1][a][k2][l];
          *(f4*)&base[(size_t)pp * Un + k2 * 64 + ug * 4] = v;
        }
      }
  }
}

// ---------------------------------------------------------------------------
// kD: reduce NP partial planes + bias + tanh, fully f4-coalesced.
// 256 blocks x 512 threads. Thread (fg=tid&31, qc=tid>>5) accumulates an f4
// over its 32-plane group; a wave reads 2x512B contiguous per instruction.
// LDS 16->1 combine, then f4 bias+tanh+store by threads 0..31.
// ---------------------------------------------------------------------------
template <int NP>
__global__ __launch_bounds__(512) void kD(const float* __restrict__ part,
                                          const float* __restrict__ bias,
                                          float* __restrict__ out) {
  __shared__ f4 red[16][33];
  const int tid = threadIdx.x;
  const int fg = tid & 31, qc = tid >> 5;   // 16 plane-groups
  constexpr int PG = NP / 16;               // planes per group
  const f4* p4 = (const f4*)part;
  const size_t g4 = (size_t)blockIdx.x * 32 + fg;  // f4-group index in [0,8192)

  f4 acc = {0.0f, 0.0f, 0.0f, 0.0f};
  for (int k = 0; k < PG; ++k) {
    f4 v = p4[(size_t)(qc * PG + k) * (Pn * Un / 4) + g4];
    acc.x += v.x; acc.y += v.y; acc.z += v.z; acc.w += v.w;
  }
  red[qc][fg] = acc;
  __syncthreads();

  if (tid < 32) {
    f4 s = red[0][fg];
#pragma unroll
    for (int q = 1; q < 16; ++q) {
      f4 v = red[q][fg];
      s.x += v.x; s.y += v.y; s.z += v.z; s.w += v.w;
    }
    f4 bv = ((const f4*)bias)[fg];   // (g4*4)&127 -> f4 index fg (block*32%32==0)
    f4 o;
    o.x = tanhf(s.x + bv.x);
    o.y = tanhf(s.y + bv.y);
    o.z = tanhf(s.z + bv.z);
    o.w = tanhf(s.w + bv.w);
    ((f4*)out)[g4] = o;
  }
}

// tanh finisher for atomic last-resort path
__global__ __launch_bounds__(256) void kD2(float* __restrict__ out,
                                           const float* __restrict__ bias) {
  const int g = blockIdx.x * 256 + threadIdx.x;
  out[g] = tanhf(out[g] + bias[g & (Un - 1)]);
}

// ---------------------------------------------------------------------------
extern "C" void kernel_launch(void* const* d_in, const int* in_sizes, int n_in,
                              void* d_out, int out_size, void* d_ws,
                              size_t ws_size, hipStream_t stream) {
  const float* in   = (const float*)d_in[0];  // [P, T]
  const float* pw   = (const float*)d_in[1];  // [P]
  const float* Kg   = (const float*)d_in[2];  // [T, U]
  const float* bias = (const float*)d_in[3];  // [U]
  const float* st   = (const float*)d_in[4];  // [P]
  float* out = (float*)d_out;                 // [P, U]
  float* wsf = (float*)d_ws;

  float* sinb = wsf;                          // NC*Pn floats (0.5 MB)
  float* part = wsf + NC * Pn;                // partial planes

  const size_t base_f = (size_t)NC * Pn;
  const size_t need1 = (base_f + (size_t)NC * Pn * Un) * 4;        // ~67.6 MB
  const size_t need2 = (base_f + (size_t)(NC / 2) * Pn * Un) * 4;  // ~34 MB

  kAB<<<Pn, 1024, 0, stream>>>(in, pw, st, sinb);

  if (ws_size >= need1) {
    kC<1, false><<<NC, 512, 0, stream>>>(in, pw, Kg, sinb, part);
    kD<NC><<<(Pn * Un / 4) / 32, 512, 0, stream>>>(part, bias, out);
  } else if (ws_size >= need2) {
    kC<2, false><<<NC / 2, 512, 0, stream>>>(in, pw, Kg, sinb, part);
    kD<NC / 2><<<(Pn * Un / 4) / 32, 512, 0, stream>>>(part, bias, out);
  } else {
    hipMemsetAsync(out, 0, (size_t)Pn * Un * sizeof(float), stream);
    kC<2, true><<<NC / 2, 512, 0, stream>>>(in, pw, Kg, sinb, out);
    kD2<<<(Pn * Un) / 256, 256, 0, stream>>>(out, bias);
  }
}